// Round 24
// baseline (156.875 us; speedup 1.0000x reference)
//
#include <hip/hip_runtime.h>
#include <hip/hip_fp16.h>
#include <math.h>

#define MROWS   65536
#define NCODES  1024
#define KD      256
#define MARGIN  0.25f

typedef unsigned short u16;
typedef __attribute__((ext_vector_type(8))) _Float16 hfrag;  // 8 fp16 = 4 VGPR
typedef __attribute__((ext_vector_type(4))) float f32x4;

// d_out bytes: [0,32M) Ah fp16 scratch; quant floats [0,64M) written by
//   gather/refine afterwards | idx floats at [64M,+256K).
// d_ws: [0,512K) Eh | [512K,+4K) esq | [640K) cnt | [640K+256,+256K) list | [1M,2M) embT
#define IOFF ((size_t)MROWS * KD)

// ---- asm-rounded fp32 add (contraction/reassociation-proof) ---------------
__device__ __forceinline__ float addrn(float a, float b) {
    float d; asm("v_add_f32 %0, %1, %2" : "=v"(d) : "v"(a), "v"(b)); return d;
}

// ---- exact VF8-IC4 sum of squares of a 256-row (stride-parameterized) -----
__device__ __forceinline__ float sumsq_vf8ic4(const float* __restrict__ xr) {
    float a[4][8];
#pragma unroll
    for (int i = 0; i < 4; ++i)
#pragma unroll
        for (int l = 0; l < 8; ++l) a[i][l] = 0.f;
#pragma unroll
    for (int m = 0; m < 8; ++m)
#pragma unroll
        for (int i = 0; i < 4; ++i)
#pragma unroll
            for (int l = 0; l < 8; ++l) {
                float v = xr[m * 32 + i * 8 + l];
                a[i][l] = fmaf(v, v, a[i][l]);
            }
    float cc[8];
#pragma unroll
    for (int l = 0; l < 8; ++l)
        cc[l] = addrn(addrn(addrn(a[0][l], a[1][l]), a[2][l]), a[3][l]);
    float u0 = addrn(cc[0], cc[4]), u1 = addrn(cc[1], cc[5]);
    float u2 = addrn(cc[2], cc[6]), u3 = addrn(cc[3], cc[7]);
    return addrn(addrn(u0, u2), addrn(u1, u3));
}

// ------- unified prep: blocks 0..63 = emb (Eh+esq+embT); 64.. = x-pack -----
// Both paths: 16 rows x 256 staged in lx[16][260]; frag = (g*8+kb), g = 16-row group.
__global__ __launch_bounds__(256)
void vq_prep(const float* __restrict__ x, const float* __restrict__ emb,
             u16* __restrict__ Ah, u16* __restrict__ Eh,
             float* __restrict__ esq, float* __restrict__ embT,
             unsigned int* __restrict__ cnt) {
    if (blockIdx.x == 0 && threadIdx.x == 0) *cnt = 0;
    __shared__ __align__(16) float lx[16 * 260];
    const int t = threadIdx.x;
    const bool is_emb = blockIdx.x < 64;
    const int g = is_emb ? blockIdx.x : (blockIdx.x - 64);   // 16-row group id
    const float* src = is_emb ? emb : x;
    u16* dh = is_emb ? Eh : Ah;
    const size_t base = (size_t)g * 16 * 256;
#pragma unroll
    for (int qq = 0; qq < 4; ++qq) {
        int i4 = qq * 256 + t;
        int row = i4 >> 6, col = (i4 & 63) * 4;
        *(float4*)(lx + row * 260 + col) = *(const float4*)(src + base + (size_t)i4 * 4);
    }
    __syncthreads();
    // fragment pack (identical math for both paths)
#pragma unroll
    for (int i = 0; i < 2; ++i) {
        int s = t + 256 * i;
        int kb = s >> 6, lane = s & 63;
        int r = lane & 15, kg = lane >> 4;
        int k0 = kb * 32 + kg * 8;
        u16 vh[8];
#pragma unroll
        for (int j = 0; j < 8; ++j) {
            float v = lx[r * 260 + k0 + j];
            vh[j] = __half_as_ushort(__float2half(v));   // RNE
        }
        size_t off = (((size_t)g * 8 + kb) * 64 + lane) * 8;
        *(ulonglong2*)(dh + off) = *(ulonglong2*)vh;
    }
    if (is_emb) {
        const int c0 = g * 16;
        if (t < 16) esq[c0 + t] = sumsq_vf8ic4(lx + t * 260);
        // embT[k][c0+col] = emb[c0+col][k]
#pragma unroll
        for (int i = 0; i < 16; ++i) {
            int k = i * 16 + (t >> 4), col = t & 15;
            embT[(size_t)k * 1024 + c0 + col] = lx[col * 260 + k];
        }
    }
}

// ------- MFMA fp16 GEMM (R19-proven K-loop): in-kernel flag/list tail ------
__global__ __launch_bounds__(256, 2)
void vq_gemm(const u16* __restrict__ Ah, const u16* __restrict__ Eh,
             const float* __restrict__ esq, float* __restrict__ idxf,
             unsigned int* __restrict__ cnt, int* __restrict__ list) {
    extern __shared__ u16 ldsA[];         // 64 KB: 64 A-frags x 512 u16
    const int t = threadIdx.x;
    const int wave = t >> 6, lane = t & 63;
    const int wm = wave >> 1, wn = wave & 1;
    const int q = lane >> 4, c = lane & 15;
    const int m0 = blockIdx.x * 128;
    const int mrb8 = blockIdx.x * 64;

#pragma unroll
    for (int u = 0; u < 16; ++u) {
        int f = wave * 16 + u;
        const u16* srcp = Ah + ((size_t)(mrb8 + f) * 64 + lane) * 8;
        __builtin_amdgcn_global_load_lds((const unsigned int*)srcp,
                                         (unsigned int*)(ldsA + f * 512), 16, 0, 0);
    }
    __syncthreads();

    auto LOADB = [&](int s, hfrag* dst) {
        const int f0 = ((s >> 3) * 64) + (wn * 4) * 8 + (s & 7);
#pragma unroll
        for (int ni = 0; ni < 4; ++ni)
            dst[ni] = *(const hfrag*)(Eh + (size_t)(f0 + ni * 8) * 512 + lane * 8);
    };
    auto LDA = [&](int s, hfrag* dst) {
        const int ks = s & 7;
#pragma unroll
        for (int mi = 0; mi < 4; ++mi)
            dst[mi] = *(const hfrag*)(ldsA + ((wm * 4 + mi) * 8 + ks) * 512 + lane * 8);
    };

    float b1[16], s2v[16], bi[16];
#pragma unroll
    for (int r = 0; r < 16; ++r) { b1[r] = INFINITY; s2v[r] = INFINITY; bi[r] = 0.f; }

    f32x4 acc[4][4];
#pragma unroll
    for (int mi = 0; mi < 4; ++mi)
#pragma unroll
        for (int ni = 0; ni < 4; ++ni) acc[mi][ni] = 0.f;

    hfrag bA[4], bB[4];
    LOADB(0, bA);
    LOADB(1, bB);

    for (int sp = 0; sp < 32; ++sp) {
        const int s0 = sp * 2, s1 = sp * 2 + 1;
        {
            hfrag nx[4];
            LOADB(s0 + 2 < 64 ? s0 + 2 : 0, nx);
            hfrag af[4];
            LDA(s0, af);
#pragma unroll
            for (int mi = 0; mi < 4; ++mi)
#pragma unroll
                for (int ni = 0; ni < 4; ++ni)
                    acc[mi][ni] = __builtin_amdgcn_mfma_f32_16x16x32_f16(af[mi], bA[ni], acc[mi][ni], 0, 0, 0);
#pragma unroll
            for (int ni = 0; ni < 4; ++ni) bA[ni] = nx[ni];
        }
        {
            hfrag nx[4];
            LOADB(s1 + 2 < 64 ? s1 + 2 : 0, nx);
            hfrag af[4];
            LDA(s1, af);
#pragma unroll
            for (int mi = 0; mi < 4; ++mi)
#pragma unroll
                for (int ni = 0; ni < 4; ++ni)
                    acc[mi][ni] = __builtin_amdgcn_mfma_f32_16x16x32_f16(af[mi], bB[ni], acc[mi][ni], 0, 0, 0);
#pragma unroll
            for (int ni = 0; ni < 4; ++ni) bB[ni] = nx[ni];
        }
        if ((s1 & 7) == 7) {
            const int nqi = s1 >> 3;
#pragma unroll
            for (int ni = 0; ni < 4; ++ni) {
                const int code = nqi * 128 + wn * 64 + ni * 16 + c;
                const float e2 = esq[code];
                const float ci = (float)code;
#pragma unroll
                for (int mi = 0; mi < 4; ++mi)
#pragma unroll
                    for (int j = 0; j < 4; ++j) {
                        const int r = mi * 4 + j;
                        float sc = fmaf(-2.f, acc[mi][ni][j], e2);
                        bool lt = sc < b1[r];
                        s2v[r] = fminf(s2v[r], lt ? b1[r] : sc);
                        if (lt) { b1[r] = sc; bi[r] = ci; }
                    }
            }
#pragma unroll
            for (int mi = 0; mi < 4; ++mi)
#pragma unroll
                for (int ni = 0; ni < 4; ++ni) acc[mi][ni] = 0.f;
        }
    }

    // merge across the 16 code-lanes (lane bits 0..3)
#pragma unroll
    for (int r = 0; r < 16; ++r) {
#pragma unroll
        for (int mm = 1; mm < 16; mm <<= 1) {
            float ob = __shfl_xor(b1[r], mm, 64);
            float os = __shfl_xor(s2v[r], mm, 64);
            float oi = __shfl_xor(bi[r], mm, 64);
            if (ob < b1[r]) { s2v[r] = fminf(b1[r], os); b1[r] = ob; bi[r] = oi; }
            else            { s2v[r] = fminf(s2v[r], ob); }
        }
    }
    // cross-wave (wn) merge via LDS (A region dead now)
    __syncthreads();
    float* sm = (float*)ldsA;   // 128 rows x 2 wn x 3 floats
    if (c == 0) {
#pragma unroll
        for (int mi = 0; mi < 4; ++mi)
#pragma unroll
            for (int j = 0; j < 4; ++j) {
                int r = mi * 4 + j;
                int row_l = wm * 64 + mi * 16 + q * 4 + j;
                sm[row_l * 6 + wn * 3 + 0] = b1[r];
                sm[row_l * 6 + wn * 3 + 1] = s2v[r];
                sm[row_l * 6 + wn * 3 + 2] = bi[r];
            }
    }
    __syncthreads();
    if (t < 128) {
        float b0 = sm[t * 6 + 0], sA = sm[t * 6 + 1], i0 = sm[t * 6 + 2];
        float bb = sm[t * 6 + 3], sB = sm[t * 6 + 4], i1 = sm[t * 6 + 5];
        float b, s2, bidx;
        if (b0 <= bb) { b = b0; bidx = i0; s2 = fminf(sA, bb); }
        else          { b = bb; bidx = i1; s2 = fminf(sB, b0); }
        int row = m0 + t;
        idxf[row] = bidx;
        if (s2 - b < MARGIN) {
            unsigned int pos = atomicAdd(cnt, 1u);
            list[pos] = row;
        }
    }
}

// ------- pure gather: quant[row] = emb[idx[row]] ---------------------------
__global__ __launch_bounds__(256)
void vq_gather(const float* __restrict__ idxf, const float* __restrict__ emb,
               float* __restrict__ quant) {
    const int t = threadIdx.x;
    const int r0 = blockIdx.x * 64;
    const int lane = t & 63, w = t >> 6;
#pragma unroll
    for (int u = 0; u < 16; ++u) {
        int rl = u * 4 + w;
        int idx = (int)idxf[r0 + rl];
        *(float4*)(quant + (size_t)(r0 + rl) * 256 + lane * 4) =
            *(const float4*)(emb + (size_t)idx * 256 + lane * 4);
    }
}

// ------- exact refine: 16 rows/group (halved embT re-reads) ----------------
__global__ __launch_bounds__(256)
void vq_refine1(const float* __restrict__ x, const float* __restrict__ emb,
                const float* __restrict__ embT, const float* __restrict__ esq,
                const int* __restrict__ list, const unsigned int* __restrict__ cnt,
                float* __restrict__ idxf, float* __restrict__ quant) {
    __shared__ __align__(16) float xs[16][260];
    __shared__ float xsq_s[16];
    __shared__ float lb[16][4];
    __shared__ int   li[16][4];
    __shared__ int   li2[16];
    const int t = threadIdx.x;
    const int wave = t >> 6, lane = t & 63;
    const unsigned int n = *cnt;
    float e2q[4];
#pragma unroll
    for (int qq = 0; qq < 4; ++qq) e2q[qq] = esq[qq * 256 + t];

    for (unsigned int g = blockIdx.x; g * 16u < n; g += gridDim.x) {
        const unsigned int r0 = g * 16u;
        const int nr = (int)min(16u, n - r0);
        __syncthreads();
#pragma unroll
        for (int u = 0; u < 4; ++u) {
            int s = u * 256 + t;
            int rr = s >> 6, l4 = s & 63;
            if (rr < nr) {
                int row = list[r0 + rr];
                *(float4*)(&xs[rr][l4 * 4]) = *(const float4*)(x + (size_t)row * 256 + l4 * 4);
            }
        }
        __syncthreads();
        if (t < nr) xsq_s[t] = sumsq_vf8ic4(&xs[t][0]);
        __syncthreads();

        float d[16][4];
#pragma unroll
        for (int r = 0; r < 16; ++r)
#pragma unroll
            for (int qq = 0; qq < 4; ++qq) d[r][qq] = 0.f;

        for (int kq = 0; kq < 64; ++kq) {
            float ev[4][4];
#pragma unroll
            for (int j = 0; j < 4; ++j)
#pragma unroll
                for (int qq = 0; qq < 4; ++qq)
                    ev[qq][j] = embT[(size_t)(kq * 4 + j) * 1024 + qq * 256 + t];
#pragma unroll
            for (int r = 0; r < 16; ++r) {
                float4 xf = *(const float4*)(&xs[r][kq * 4]);
#pragma unroll
                for (int qq = 0; qq < 4; ++qq) {
                    d[r][qq] = fmaf(xf.x, ev[qq][0], d[r][qq]);
                    d[r][qq] = fmaf(xf.y, ev[qq][1], d[r][qq]);
                    d[r][qq] = fmaf(xf.z, ev[qq][2], d[r][qq]);
                    d[r][qq] = fmaf(xf.w, ev[qq][3], d[r][qq]);
                }
            }
        }
#pragma unroll
        for (int r = 0; r < 16; ++r) {
            float sv = INFINITY; int bc = 0x7fffffff;
#pragma unroll
            for (int qq = 0; qq < 4; ++qq) {   // ascending code order -> min idx on ties
                float s = addrn(fmaf(-2.f, d[r][qq], xsq_s[r]), e2q[qq]);
                if (s < sv) { sv = s; bc = qq * 256 + t; }
            }
#pragma unroll
            for (int mm = 1; mm < 64; mm <<= 1) {
                float ob = __shfl_xor(sv, mm, 64);
                int oi = __shfl_xor(bc, mm, 64);
                if (ob < sv || (ob == sv && oi < bc)) { sv = ob; bc = oi; }
            }
            if (lane == 0) { lb[r][wave] = sv; li[r][wave] = bc; }
        }
        __syncthreads();
        if (t < nr) {
            float best = lb[t][0]; int bix = li[t][0];
#pragma unroll
            for (int w = 1; w < 4; ++w) {
                float ob = lb[t][w]; int oi = li[t][w];
                if (ob < best || (ob == best && oi < bix)) { best = ob; bix = oi; }
            }
            idxf[list[r0 + t]] = (float)bix;
            li2[t] = bix;
        }
        __syncthreads();
#pragma unroll
        for (int rr = 0; rr < 4; ++rr) {
            int rl = wave * 4 + rr;
            if (rl < nr) {
                int row = list[r0 + rl];
                int idx = li2[rl];
                *(float4*)(quant + (size_t)row * 256 + lane * 4) =
                    *(const float4*)(emb + (size_t)idx * 256 + lane * 4);
            }
        }
    }
}

extern "C" void kernel_launch(void* const* d_in, const int* in_sizes, int n_in,
                              void* d_out, int out_size, void* d_ws, size_t ws_size,
                              hipStream_t stream) {
    const float* x   = (const float*)d_in[0];
    const float* emb = (const float*)d_in[1];
    float* out  = (float*)d_out;
    float* idxf = out + IOFF;

    u16* Ah = (u16*)out;                          // [0, 32MB) scratch

    char* ws = (char*)d_ws;
    u16* Eh    = (u16*)(ws);
    float* esq = (float*)(ws + (512 << 10));
    unsigned int* cnt = (unsigned int*)(ws + (640 << 10));
    int* list  = (int*)(ws + (640 << 10) + 256);
    float* embT = (float*)(ws + (1 << 20));

    vq_prep<<<dim3(64 + MROWS / 16), dim3(256), 0, stream>>>(x, emb, Ah, Eh, esq, embT, cnt);
    vq_gemm<<<dim3(MROWS / 128), dim3(256), 65536, stream>>>(Ah, Eh, esq, idxf, cnt, list);
    vq_gather<<<dim3(MROWS / 64), dim3(256), 0, stream>>>(idxf, emb, out);
    vq_refine1<<<dim3(512), dim3(256), 0, stream>>>(x, emb, embT, esq, list, cnt, idxf, out);
}

// Round 25
// 122.291 us; speedup vs baseline: 1.2828x; 1.2828x over previous
//
#include <hip/hip_runtime.h>
#include <hip/hip_fp16.h>
#include <math.h>

#define MROWS   65536
#define NCODES  1024
#define KD      256
#define MARGIN  0.25f

typedef unsigned short u16;
typedef __attribute__((ext_vector_type(8))) _Float16 hfrag;  // 8 fp16 = 4 VGPR
typedef __attribute__((ext_vector_type(4))) float f32x4;

// d_out bytes: [0,32M) Ah fp16 scratch; quant floats [0,64M) written by
//   gather/refine afterwards | idx floats at [64M,+256K).
// d_ws: [0,512K) Eh | [512K,+4K) esq | [640K) cnt | [640K+256,+256K) list | [1M,2M) embT
#define IOFF ((size_t)MROWS * KD)

// ---- asm-rounded fp32 add (contraction/reassociation-proof) ---------------
__device__ __forceinline__ float addrn(float a, float b) {
    float d; asm("v_add_f32 %0, %1, %2" : "=v"(d) : "v"(a), "v"(b)); return d;
}

// ---- exact VF8-IC4 sum of squares of a 256-row -----------------------------
__device__ __forceinline__ float sumsq_vf8ic4(const float* __restrict__ xr) {
    float a[4][8];
#pragma unroll
    for (int i = 0; i < 4; ++i)
#pragma unroll
        for (int l = 0; l < 8; ++l) a[i][l] = 0.f;
#pragma unroll
    for (int m = 0; m < 8; ++m)
#pragma unroll
        for (int i = 0; i < 4; ++i)
#pragma unroll
            for (int l = 0; l < 8; ++l) {
                float v = xr[m * 32 + i * 8 + l];
                a[i][l] = fmaf(v, v, a[i][l]);
            }
    float cc[8];
#pragma unroll
    for (int l = 0; l < 8; ++l)
        cc[l] = addrn(addrn(addrn(a[0][l], a[1][l]), a[2][l]), a[3][l]);
    float u0 = addrn(cc[0], cc[4]), u1 = addrn(cc[1], cc[5]);
    float u2 = addrn(cc[2], cc[6]), u3 = addrn(cc[3], cc[7]);
    return addrn(addrn(u0, u2), addrn(u1, u3));
}

// ------- unified prep: blocks 0..63 = emb (Eh+esq+embT); 64.. = x-pack -----
__global__ __launch_bounds__(256)
void vq_prep(const float* __restrict__ x, const float* __restrict__ emb,
             u16* __restrict__ Ah, u16* __restrict__ Eh,
             float* __restrict__ esq, float* __restrict__ embT,
             unsigned int* __restrict__ cnt) {
    if (blockIdx.x == 0 && threadIdx.x == 0) *cnt = 0;
    __shared__ __align__(16) float lx[16 * 260];
    const int t = threadIdx.x;
    const bool is_emb = blockIdx.x < 64;
    const int g = is_emb ? blockIdx.x : (blockIdx.x - 64);   // 16-row group id
    const float* src = is_emb ? emb : x;
    u16* dh = is_emb ? Eh : Ah;
    const size_t base = (size_t)g * 16 * 256;
#pragma unroll
    for (int qq = 0; qq < 4; ++qq) {
        int i4 = qq * 256 + t;
        int row = i4 >> 6, col = (i4 & 63) * 4;
        *(float4*)(lx + row * 260 + col) = *(const float4*)(src + base + (size_t)i4 * 4);
    }
    __syncthreads();
#pragma unroll
    for (int i = 0; i < 2; ++i) {
        int s = t + 256 * i;
        int kb = s >> 6, lane = s & 63;
        int r = lane & 15, kg = lane >> 4;
        int k0 = kb * 32 + kg * 8;
        u16 vh[8];
#pragma unroll
        for (int j = 0; j < 8; ++j) {
            float v = lx[r * 260 + k0 + j];
            vh[j] = __half_as_ushort(__float2half(v));   // RNE
        }
        size_t off = (((size_t)g * 8 + kb) * 64 + lane) * 8;
        *(ulonglong2*)(dh + off) = *(ulonglong2*)vh;
    }
    if (is_emb) {
        const int c0 = g * 16;
        if (t < 16) esq[c0 + t] = sumsq_vf8ic4(lx + t * 260);
#pragma unroll
        for (int i = 0; i < 16; ++i) {
            int k = i * 16 + (t >> 4), col = t & 15;
            embT[(size_t)k * 1024 + c0 + col] = lx[col * 260 + k];
        }
    }
}

// ------- MFMA fp16 GEMM (R19-proven K-loop): in-kernel flag/list tail ------
__global__ __launch_bounds__(256, 2)
void vq_gemm(const u16* __restrict__ Ah, const u16* __restrict__ Eh,
             const float* __restrict__ esq, float* __restrict__ idxf,
             unsigned int* __restrict__ cnt, int* __restrict__ list) {
    extern __shared__ u16 ldsA[];         // 64 KB: 64 A-frags x 512 u16
    const int t = threadIdx.x;
    const int wave = t >> 6, lane = t & 63;
    const int wm = wave >> 1, wn = wave & 1;
    const int q = lane >> 4, c = lane & 15;
    const int m0 = blockIdx.x * 128;
    const int mrb8 = blockIdx.x * 64;

#pragma unroll
    for (int u = 0; u < 16; ++u) {
        int f = wave * 16 + u;
        const u16* srcp = Ah + ((size_t)(mrb8 + f) * 64 + lane) * 8;
        __builtin_amdgcn_global_load_lds((const unsigned int*)srcp,
                                         (unsigned int*)(ldsA + f * 512), 16, 0, 0);
    }
    __syncthreads();

    auto LOADB = [&](int s, hfrag* dst) {
        const int f0 = ((s >> 3) * 64) + (wn * 4) * 8 + (s & 7);
#pragma unroll
        for (int ni = 0; ni < 4; ++ni)
            dst[ni] = *(const hfrag*)(Eh + (size_t)(f0 + ni * 8) * 512 + lane * 8);
    };
    auto LDA = [&](int s, hfrag* dst) {
        const int ks = s & 7;
#pragma unroll
        for (int mi = 0; mi < 4; ++mi)
            dst[mi] = *(const hfrag*)(ldsA + ((wm * 4 + mi) * 8 + ks) * 512 + lane * 8);
    };

    float b1[16], s2v[16], bi[16];
#pragma unroll
    for (int r = 0; r < 16; ++r) { b1[r] = INFINITY; s2v[r] = INFINITY; bi[r] = 0.f; }

    f32x4 acc[4][4];
#pragma unroll
    for (int mi = 0; mi < 4; ++mi)
#pragma unroll
        for (int ni = 0; ni < 4; ++ni) acc[mi][ni] = 0.f;

    hfrag bA[4], bB[4];
    LOADB(0, bA);
    LOADB(1, bB);

    for (int sp = 0; sp < 32; ++sp) {
        const int s0 = sp * 2, s1 = sp * 2 + 1;
        {
            hfrag nx[4];
            LOADB(s0 + 2 < 64 ? s0 + 2 : 0, nx);
            hfrag af[4];
            LDA(s0, af);
#pragma unroll
            for (int mi = 0; mi < 4; ++mi)
#pragma unroll
                for (int ni = 0; ni < 4; ++ni)
                    acc[mi][ni] = __builtin_amdgcn_mfma_f32_16x16x32_f16(af[mi], bA[ni], acc[mi][ni], 0, 0, 0);
#pragma unroll
            for (int ni = 0; ni < 4; ++ni) bA[ni] = nx[ni];
        }
        {
            hfrag nx[4];
            LOADB(s1 + 2 < 64 ? s1 + 2 : 0, nx);
            hfrag af[4];
            LDA(s1, af);
#pragma unroll
            for (int mi = 0; mi < 4; ++mi)
#pragma unroll
                for (int ni = 0; ni < 4; ++ni)
                    acc[mi][ni] = __builtin_amdgcn_mfma_f32_16x16x32_f16(af[mi], bB[ni], acc[mi][ni], 0, 0, 0);
#pragma unroll
            for (int ni = 0; ni < 4; ++ni) bB[ni] = nx[ni];
        }
        if ((s1 & 7) == 7) {
            const int nqi = s1 >> 3;
#pragma unroll
            for (int ni = 0; ni < 4; ++ni) {
                const int code = nqi * 128 + wn * 64 + ni * 16 + c;
                const float e2 = esq[code];
                const float ci = (float)code;
#pragma unroll
                for (int mi = 0; mi < 4; ++mi)
#pragma unroll
                    for (int j = 0; j < 4; ++j) {
                        const int r = mi * 4 + j;
                        float sc = fmaf(-2.f, acc[mi][ni][j], e2);
                        bool lt = sc < b1[r];
                        s2v[r] = fminf(s2v[r], lt ? b1[r] : sc);
                        if (lt) { b1[r] = sc; bi[r] = ci; }
                    }
            }
#pragma unroll
            for (int mi = 0; mi < 4; ++mi)
#pragma unroll
                for (int ni = 0; ni < 4; ++ni) acc[mi][ni] = 0.f;
        }
    }

    // merge across the 16 code-lanes (lane bits 0..3)
#pragma unroll
    for (int r = 0; r < 16; ++r) {
#pragma unroll
        for (int mm = 1; mm < 16; mm <<= 1) {
            float ob = __shfl_xor(b1[r], mm, 64);
            float os = __shfl_xor(s2v[r], mm, 64);
            float oi = __shfl_xor(bi[r], mm, 64);
            if (ob < b1[r]) { s2v[r] = fminf(b1[r], os); b1[r] = ob; bi[r] = oi; }
            else            { s2v[r] = fminf(s2v[r], ob); }
        }
    }
    // cross-wave (wn) merge via LDS (A region dead now)
    __syncthreads();
    float* sm = (float*)ldsA;   // 128 rows x 2 wn x 3 floats
    if (c == 0) {
#pragma unroll
        for (int mi = 0; mi < 4; ++mi)
#pragma unroll
            for (int j = 0; j < 4; ++j) {
                int r = mi * 4 + j;
                int row_l = wm * 64 + mi * 16 + q * 4 + j;
                sm[row_l * 6 + wn * 3 + 0] = b1[r];
                sm[row_l * 6 + wn * 3 + 1] = s2v[r];
                sm[row_l * 6 + wn * 3 + 2] = bi[r];
            }
    }
    __syncthreads();
    if (t < 128) {
        float b0 = sm[t * 6 + 0], sA = sm[t * 6 + 1], i0 = sm[t * 6 + 2];
        float bb = sm[t * 6 + 3], sB = sm[t * 6 + 4], i1 = sm[t * 6 + 5];
        float b, s2, bidx;
        if (b0 <= bb) { b = b0; bidx = i0; s2 = fminf(sA, bb); }
        else          { b = bb; bidx = i1; s2 = fminf(sB, b0); }
        int row = m0 + t;
        idxf[row] = bidx;
        if (s2 - b < MARGIN) {
            unsigned int pos = atomicAdd(cnt, 1u);
            list[pos] = row;
        }
    }
}

// ------- pure gather: quant[row] = emb[idx[row]] ---------------------------
__global__ __launch_bounds__(256)
void vq_gather(const float* __restrict__ idxf, const float* __restrict__ emb,
               float* __restrict__ quant) {
    const int t = threadIdx.x;
    const int r0 = blockIdx.x * 64;
    const int lane = t & 63, w = t >> 6;
#pragma unroll
    for (int u = 0; u < 16; ++u) {
        int rl = u * 4 + w;
        int idx = (int)idxf[r0 + rl];
        *(float4*)(quant + (size_t)(r0 + rl) * 256 + lane * 4) =
            *(const float4*)(emb + (size_t)idx * 256 + lane * 4);
    }
}

// ------- exact refine: 8 rows/group, embT coalesced; fixes idx AND quant ---
__global__ __launch_bounds__(256)
void vq_refine1(const float* __restrict__ x, const float* __restrict__ emb,
                const float* __restrict__ embT, const float* __restrict__ esq,
                const int* __restrict__ list, const unsigned int* __restrict__ cnt,
                float* __restrict__ idxf, float* __restrict__ quant) {
    __shared__ __align__(16) float xs[8][260];
    __shared__ float xsq_s[8];
    __shared__ float lb[8][4];
    __shared__ int   li[8][4];
    __shared__ int   li2[8];
    const int t = threadIdx.x;
    const int wave = t >> 6, lane = t & 63;
    const unsigned int n = *cnt;
    float e2q[4];
#pragma unroll
    for (int qq = 0; qq < 4; ++qq) e2q[qq] = esq[qq * 256 + t];

    for (unsigned int g = blockIdx.x; g * 8u < n; g += gridDim.x) {
        const unsigned int r0 = g * 8u;
        const int nr = (int)min(8u, n - r0);
        __syncthreads();
#pragma unroll
        for (int u = 0; u < 2; ++u) {
            int s = u * 256 + t;
            int rr = s >> 6, l4 = s & 63;
            if (rr < nr) {
                int row = list[r0 + rr];
                *(float4*)(&xs[rr][l4 * 4]) = *(const float4*)(x + (size_t)row * 256 + l4 * 4);
            }
        }
        __syncthreads();
        if (t < nr) xsq_s[t] = sumsq_vf8ic4(&xs[t][0]);
        __syncthreads();

        float d[8][4];
#pragma unroll
        for (int r = 0; r < 8; ++r)
#pragma unroll
            for (int qq = 0; qq < 4; ++qq) d[r][qq] = 0.f;

        for (int kq = 0; kq < 64; ++kq) {
            float ev[4][4];
#pragma unroll
            for (int j = 0; j < 4; ++j)
#pragma unroll
                for (int qq = 0; qq < 4; ++qq)
                    ev[qq][j] = embT[(size_t)(kq * 4 + j) * 1024 + qq * 256 + t];
            float4 xf[8];
#pragma unroll
            for (int r = 0; r < 8; ++r) xf[r] = *(const float4*)(&xs[r][kq * 4]);
#pragma unroll
            for (int r = 0; r < 8; ++r)
#pragma unroll
                for (int qq = 0; qq < 4; ++qq) {
                    d[r][qq] = fmaf(xf[r].x, ev[qq][0], d[r][qq]);
                    d[r][qq] = fmaf(xf[r].y, ev[qq][1], d[r][qq]);
                    d[r][qq] = fmaf(xf[r].z, ev[qq][2], d[r][qq]);
                    d[r][qq] = fmaf(xf[r].w, ev[qq][3], d[r][qq]);
                }
        }
#pragma unroll
        for (int r = 0; r < 8; ++r) {
            float sv = INFINITY; int bc = 0x7fffffff;
#pragma unroll
            for (int qq = 0; qq < 4; ++qq) {   // ascending code order -> min idx on ties
                float s = addrn(fmaf(-2.f, d[r][qq], xsq_s[r]), e2q[qq]);
                if (s < sv) { sv = s; bc = qq * 256 + t; }
            }
#pragma unroll
            for (int mm = 1; mm < 64; mm <<= 1) {
                float ob = __shfl_xor(sv, mm, 64);
                int oi = __shfl_xor(bc, mm, 64);
                if (ob < sv || (ob == sv && oi < bc)) { sv = ob; bc = oi; }
            }
            if (lane == 0) { lb[r][wave] = sv; li[r][wave] = bc; }
        }
        __syncthreads();
        if (t < nr) {
            float best = lb[t][0]; int bix = li[t][0];
#pragma unroll
            for (int w = 1; w < 4; ++w) {
                float ob = lb[t][w]; int oi = li[t][w];
                if (ob < best || (ob == best && oi < bix)) { best = ob; bix = oi; }
            }
            idxf[list[r0 + t]] = (float)bix;
            li2[t] = bix;
        }
        __syncthreads();
#pragma unroll
        for (int rr = 0; rr < 2; ++rr) {
            int rl = wave * 2 + rr;
            if (rl < nr) {
                int row = list[r0 + rl];
                int idx = li2[rl];
                *(float4*)(quant + (size_t)row * 256 + lane * 4) =
                    *(const float4*)(emb + (size_t)idx * 256 + lane * 4);
            }
        }
    }
}

extern "C" void kernel_launch(void* const* d_in, const int* in_sizes, int n_in,
                              void* d_out, int out_size, void* d_ws, size_t ws_size,
                              hipStream_t stream) {
    const float* x   = (const float*)d_in[0];
    const float* emb = (const float*)d_in[1];
    float* out  = (float*)d_out;
    float* idxf = out + IOFF;

    u16* Ah = (u16*)out;                          // [0, 32MB) scratch

    char* ws = (char*)d_ws;
    u16* Eh    = (u16*)(ws);
    float* esq = (float*)(ws + (512 << 10));
    unsigned int* cnt = (unsigned int*)(ws + (640 << 10));
    int* list  = (int*)(ws + (640 << 10) + 256);
    float* embT = (float*)(ws + (1 << 20));

    vq_prep<<<dim3(64 + MROWS / 16), dim3(256), 0, stream>>>(x, emb, Ah, Eh, esq, embT, cnt);
    vq_gemm<<<dim3(MROWS / 128), dim3(256), 65536, stream>>>(Ah, Eh, esq, idxf, cnt, list);
    vq_gather<<<dim3(MROWS / 64), dim3(256), 0, stream>>>(idxf, emb, out);
    vq_refine1<<<dim3(512), dim3(256), 0, stream>>>(x, emb, embT, esq, list, cnt, idxf, out);
}